// Round 7
// baseline (316.896 us; speedup 1.0000x reference)
//
#include <hip/hip_runtime.h>
#include <hip/hip_bf16.h>
#include <cstdint>
#include <cstddef>

// Problem constants (fixed shapes)
#define Bn   4
#define Sn   4096
#define Nn   16384
#define CSn  256
#define COn  128
#define CINn 384
#define MTOT 65536   // B*N

using short8 = short __attribute__((ext_vector_type(8)));
using f32x4  = float __attribute__((ext_vector_type(4)));
using f32x2  = float __attribute__((ext_vector_type(2)));

static __device__ __forceinline__ float bf2f(unsigned short u){
  unsigned int x = ((unsigned int)u) << 16;
  return __builtin_bit_cast(float, x);
}
static __device__ __forceinline__ unsigned short f2bf(float f){
  unsigned int x = __builtin_bit_cast(unsigned int, f);
  x += 0x7fffu + ((x >> 16) & 1u);   // RNE
  return (unsigned short)(x >> 16);
}

// ---------------- KNN ----------------
// branchy insert used only in the tiny merges
static __device__ __forceinline__ void top3_insert(float d, int s,
    float& d0, float& d1, float& d2, int& i0, int& i1, int& i2){
  if (d < d2){
    if (d < d1){
      d2 = d1; i2 = i1;
      if (d < d0){ d1 = d0; i1 = i0; d0 = d; i0 = s; }
      else       { d1 = d;  i1 = s; }
    } else { d2 = d; i2 = s; }
  }
}

// branch-free top3 maintenance (R6-verified): strict '<', ascending scan order
static __device__ __forceinline__ void top3_bf(float dd, int sidx,
    float& d0, float& d1, float& d2, int& i0, int& i1, int& i2){
  const bool c0 = dd < d0, c1 = dd < d1, c2 = dd < d2;
  const float od0 = d0, od1 = d1;
  d0 = fminf(dd, od0);
  d1 = __builtin_amdgcn_fmed3f(dd, od0, od1);
  d2 = __builtin_amdgcn_fmed3f(dd, od1, d2);
  i2 = c2 ? (c1 ? i1 : sidx) : i2;    // old i1
  i1 = c1 ? (c0 ? i0 : sidx) : i1;    // old i0
  i0 = c0 ? sidx : i0;
}

// 1024 blocks x 128 threads (2 waves). Block = 64 queries (lane = query);
// wave w scans S-half [w*2048,(w+1)*2048), split into chain A = first 1024
// and chain B = second 1024 (all A indices < all B indices -> strict-'<'
// A-then-B merge preserves top_k tie-break). Keys are staged per-wave into
// double-buffered LDS chunks in PAIR-INTERLEAVED layout:
//   cb[2i]   = {xA, xB, yA, yB}
//   cb[2i+1] = {zA, zB, ssA, ssB}
// so uniform-address broadcast ds_reads land in adjacent VGPR pairs and the
// distance math runs PACKED (v_pk_*_f32 over f32x2, 2 keys per op).
// Per-component rounding identical to scalar: fma(-2, dot, add(qq,ss)),
// dot = fma(z, fma(y, mul(x))) -> bit-exact vs rounds 1-6 (no tie flips).
// ss computed inline from sxyz (skey kernel eliminated).
// No barriers in the main loop (wave-private buffers); async-split staging:
// next chunk's global loads issue before the scan, ds_writes after.
__global__ __launch_bounds__(128) void knn_kernel(
    const float* __restrict__ sxyz, const float* __restrict__ oxyz,
    float* __restrict__ kw, int* __restrict__ ki)
{
  __shared__ float4 cb[2][2][512];   // 32 KB: [wave][dbuf][2*256 float4]
  __shared__ float  md[2][64][3];
  __shared__ int    mi[2][64][3];

  const int b    = blockIdx.x >> 8;      // 256 blocks per batch
  const int qblk = blockIdx.x & 255;
  const int lane = threadIdx.x & 63;
  const int wave = threadIdx.x >> 6;     // 0..1 = S-half
  const int n    = qblk*64 + lane;
  const float* op = oxyz + ((size_t)b*Nn + n)*3;
  const float px = op[0], py = op[1], pz = op[2];
  const float qq = __fadd_rn(__fadd_rn(__fmul_rn(px,px), __fmul_rn(py,py)), __fmul_rn(pz,pz));
  const f32x2 px2 = {px,px}, py2 = {py,py}, pz2 = {pz,pz}, qq2 = {qq,qq};
  const f32x2 m2  = {-2.0f,-2.0f};

  const float* sx = sxyz + (size_t)b*Sn*3;
  const int halfbase = wave*2048;        // chain A: +[0,1024), chain B: +[1024,2048)

  float ax[4], ay[4], az[4], bx[4], by[4], bz[4];

  // load round-0 keys (A chunk 0 / B chunk 0)
  #pragma unroll
  for (int it = 0; it < 4; ++it){
    int ja = halfbase + it*64 + lane;
    int jb = ja + 1024;
    ax[it]=sx[ja*3+0]; ay[it]=sx[ja*3+1]; az[it]=sx[ja*3+2];
    bx[it]=sx[jb*3+0]; by[it]=sx[jb*3+1]; bz[it]=sx[jb*3+2];
  }
  // write round 0
  #pragma unroll
  for (int it = 0; it < 4; ++it){
    float assv = __fadd_rn(__fadd_rn(__fmul_rn(ax[it],ax[it]), __fmul_rn(ay[it],ay[it])), __fmul_rn(az[it],az[it]));
    float bssv = __fadd_rn(__fadd_rn(__fmul_rn(bx[it],bx[it]), __fmul_rn(by[it],by[it])), __fmul_rn(bz[it],bz[it]));
    int j = it*64 + lane;
    cb[wave][0][2*j]   = make_float4(ax[it], bx[it], ay[it], by[it]);
    cb[wave][0][2*j+1] = make_float4(az[it], bz[it], assv, bssv);
  }

  float dA0=3.4e38f,dA1=3.4e38f,dA2=3.4e38f; int iA0=0,iA1=0,iA2=0;
  float dB0=3.4e38f,dB1=3.4e38f,dB2=3.4e38f; int iB0=0,iB1=0,iB2=0;

  int cur = 0;
  for (int c = 0; c < 4; ++c){
    if (c < 3){                          // issue next round's loads EARLY
      #pragma unroll
      for (int it = 0; it < 4; ++it){
        int ja = halfbase + (c+1)*256 + it*64 + lane;
        int jb = ja + 1024;
        ax[it]=sx[ja*3+0]; ay[it]=sx[ja*3+1]; az[it]=sx[ja*3+2];
        bx[it]=sx[jb*3+0]; by[it]=sx[jb*3+1]; bz[it]=sx[jb*3+2];
      }
    }
    const int sbA = halfbase + c*256;     // chain-A index base this round
    #pragma unroll 8
    for (int i = 0; i < 256; ++i){
      const f32x2* kp = reinterpret_cast<const f32x2*>(&cb[wave][cur][2*i]);
      f32x2 kx = kp[0], ky = kp[1], kz = kp[2], kss = kp[3];
      f32x2 dot = kx * px2;
      dot = __builtin_elementwise_fma(ky, py2, dot);
      dot = __builtin_elementwise_fma(kz, pz2, dot);
      f32x2 sm = qq2 + kss;
      f32x2 dd = __builtin_elementwise_fma(m2, dot, sm);
      top3_bf(dd.x, sbA + i,        dA0,dA1,dA2, iA0,iA1,iA2);
      top3_bf(dd.y, sbA + i + 1024, dB0,dB1,dB2, iB0,iB1,iB2);
    }
    if (c < 3){                          // write next round AFTER the scan
      int nxt = cur ^ 1;
      #pragma unroll
      for (int it = 0; it < 4; ++it){
        float assv = __fadd_rn(__fadd_rn(__fmul_rn(ax[it],ax[it]), __fmul_rn(ay[it],ay[it])), __fmul_rn(az[it],az[it]));
        float bssv = __fadd_rn(__fadd_rn(__fmul_rn(bx[it],bx[it]), __fmul_rn(by[it],by[it])), __fmul_rn(bz[it],bz[it]));
        int j = it*64 + lane;
        cb[wave][nxt][2*j]   = make_float4(ax[it], bx[it], ay[it], by[it]);
        cb[wave][nxt][2*j+1] = make_float4(az[it], bz[it], assv, bssv);
      }
      cur = nxt;
    }
  }

  // per-wave A/B merge: all A indices < all B indices -> strict '<' correct
  {
    float e0=dA0, e1=dA1, e2=dA2; int j0=iA0, j1=iA1, j2=iA2;
    top3_insert(dB0, iB0, e0,e1,e2, j0,j1,j2);
    top3_insert(dB1, iB1, e0,e1,e2, j0,j1,j2);
    top3_insert(dB2, iB2, e0,e1,e2, j0,j1,j2);
    md[wave][lane][0]=e0; md[wave][lane][1]=e1; md[wave][lane][2]=e2;
    mi[wave][lane][0]=j0; mi[wave][lane][1]=j1; mi[wave][lane][2]=j2;
  }
  __syncthreads();
  if (threadIdx.x < 64){
    float e0=md[0][lane][0], e1=md[0][lane][1], e2=md[0][lane][2];
    int   j0=mi[0][lane][0], j1=mi[0][lane][1], j2=mi[0][lane][2];
    top3_insert(md[1][lane][0], mi[1][lane][0], e0,e1,e2, j0,j1,j2);
    top3_insert(md[1][lane][1], mi[1][lane][1], e0,e1,e2, j0,j1,j2);
    top3_insert(md[1][lane][2], mi[1][lane][2], e0,e1,e2, j0,j1,j2);
    float wa = 1.0f/(e0+1e-8f), wb = 1.0f/(e1+1e-8f), wc = 1.0f/(e2+1e-8f);
    float sm = __fadd_rn(__fadd_rn(wa, wb), wc);
    size_t base = ((size_t)b*Nn + n)*3;
    kw[base+0] = wa/sm; kw[base+1] = wb/sm; kw[base+2] = wc/sm;
    ki[base+0] = j0;    ki[base+1] = j1;    ki[base+2] = j2;
  }
}

// ------------- interpolate + concat -> x [M][384] bf16 -------------
__global__ __launch_bounds__(256) void interp_kernel(
    const float* __restrict__ sfeat, const float* __restrict__ ofeat,
    const float* __restrict__ kw, const int* __restrict__ ki,
    unsigned short* __restrict__ X)
{
  const int c  = threadIdx.x;          // channel 0..255
  const int m0 = blockIdx.x * 16;      // 16 points per block
  for (int p = 0; p < 16; ++p){
    const int m = m0 + p;
    const int b = m >> 14;             // N = 16384
    const float w0v = kw[(size_t)m*3+0], w1v = kw[(size_t)m*3+1], w2v = kw[(size_t)m*3+2];
    const int   i0  = ki[(size_t)m*3+0], i1  = ki[(size_t)m*3+1], i2  = ki[(size_t)m*3+2];
    const float* sb = sfeat + (size_t)b * Sn * CSn;
    float v = __fmaf_rn(w2v, sb[(size_t)i2*CSn + c],
              __fmaf_rn(w1v, sb[(size_t)i1*CSn + c],
              __fmul_rn(w0v, sb[(size_t)i0*CSn + c])));
    X[(size_t)m*CINn + COn + c] = f2bf(v);
    if (c < COn) X[(size_t)m*CINn + c] = f2bf(ofeat[(size_t)m*COn + c]);
  }
}

// ------------- fp32 -> bf16 weight conversion -------------
__global__ __launch_bounds__(256) void cvtw_kernel(
    const float* __restrict__ w0, const float* __restrict__ w1,
    unsigned short* __restrict__ w0b, unsigned short* __restrict__ w1b)
{
  int i = blockIdx.x*256 + threadIdx.x;
  if (i < 256*384) w0b[i] = f2bf(w0[i]);
  int j = i - 256*384;
  if (j >= 0 && j < 256*256) w1b[j] = f2bf(w1[j]);
}

// ------------- GEMM: Y[M][256] = A[M][KDIM] @ W[256][KDIM]^T + bias ----------
// BM=128, BN=256 (full), BK=64. 4 waves, wave w owns cols [w*64, w*64+64).
// BNRELU prologue computes BN0 scale/shift IN-KERNEL from gemm0's stats
// (bnfin kernel folded away), then A' = relu(A*scale + shift) during staging.
// Epilogue: bf16 store + per-channel sum/sumsq atomics for BN stats.
template<int KDIM, bool BNRELU>
__global__ __launch_bounds__(256) void gemm_kernel(
    const unsigned short* __restrict__ A,
    const unsigned short* __restrict__ W,
    const float* __restrict__ bias,
    const float* __restrict__ s0sum,
    const float* __restrict__ s0sq,
    const float* __restrict__ bng,
    const float* __restrict__ bnbt,
    unsigned short* __restrict__ Y,
    float* __restrict__ osum,
    float* __restrict__ osq)
{
  __shared__ unsigned short As[128*64];   // 16 KB, XOR-swizzled 16B chunks
  __shared__ unsigned short Bs[256*64];   // 32 KB
  __shared__ float lsc[256], lsh[256];
  const int tid  = threadIdx.x;
  const int lane = tid & 63;
  const int wave = tid >> 6;
  const size_t mbase = (size_t)blockIdx.x * 128;
  if constexpr (BNRELU){
    float mean = s0sum[tid] * (1.0f/65536.0f);
    float var  = s0sq[tid] * (1.0f/65536.0f) - mean*mean;
    float s = bng[tid] / sqrtf(var + 1e-5f);
    lsc[tid] = s;
    lsh[tid] = __fmaf_rn(-mean, s, bnbt[tid]);
  }
  f32x4 acc[8][4];
  #pragma unroll
  for (int m2 = 0; m2 < 8; ++m2)
    #pragma unroll
    for (int n2 = 0; n2 < 4; ++n2) acc[m2][n2] = f32x4{0.f,0.f,0.f,0.f};
  __syncthreads();

  for (int k0 = 0; k0 < KDIM; k0 += 64){
    if (k0) __syncthreads();
    // stage A: 128 rows x 8 chunks(16B) = 1024 chunks, 4/thread
    #pragma unroll
    for (int i = 0; i < 4; ++i){
      int cid = tid + 256*i;
      int row = cid >> 3, c8 = cid & 7;
      short8 v = *reinterpret_cast<const short8*>(A + (mbase+row)*KDIM + k0 + c8*8);
      if constexpr (BNRELU){
        #pragma unroll
        for (int j = 0; j < 8; ++j){
          int kc = k0 + c8*8 + j;
          float f = bf2f((unsigned short)v[j]);
          f = fmaxf(__fmaf_rn(f, lsc[kc], lsh[kc]), 0.0f);
          v[j] = (short)f2bf(f);
        }
      }
      *reinterpret_cast<short8*>(reinterpret_cast<char*>(As) + row*128 + ((c8 ^ (row&7)) << 4)) = v;
    }
    // stage B (weights): 256 rows x 8 chunks = 2048 chunks, 8/thread
    #pragma unroll
    for (int i = 0; i < 8; ++i){
      int cid = tid + 256*i;
      int row = cid >> 3, c8 = cid & 7;
      short8 v = *reinterpret_cast<const short8*>(W + (size_t)row*KDIM + k0 + c8*8);
      *reinterpret_cast<short8*>(reinterpret_cast<char*>(Bs) + row*128 + ((c8 ^ (row&7)) << 4)) = v;
    }
    __syncthreads();
    #pragma unroll
    for (int kk = 0; kk < 2; ++kk){
      short8 af[8], bv[4];
      #pragma unroll
      for (int m2 = 0; m2 < 8; ++m2){
        int row = m2*16 + (lane & 15);
        int c8  = kk*4 + (lane >> 4);
        af[m2] = *reinterpret_cast<const short8*>(reinterpret_cast<char*>(As) + row*128 + ((c8 ^ (row&7)) << 4));
      }
      #pragma unroll
      for (int n2 = 0; n2 < 4; ++n2){
        int row = wave*64 + n2*16 + (lane & 15);
        int c8  = kk*4 + (lane >> 4);
        bv[n2] = *reinterpret_cast<const short8*>(reinterpret_cast<char*>(Bs) + row*128 + ((c8 ^ (row&7)) << 4));
      }
      #pragma unroll
      for (int m2 = 0; m2 < 8; ++m2)
        #pragma unroll
        for (int n2 = 0; n2 < 4; ++n2)
          acc[m2][n2] = __builtin_amdgcn_mfma_f32_16x16x32_bf16(af[m2], bv[n2], acc[m2][n2], 0, 0, 0);
    }
  }

  // epilogue: C/D layout col = lane&15, row = (lane>>4)*4 + j  [m89-verified]
  const int colg0 = wave*64;
  float spart[4] = {0,0,0,0}, qpart[4] = {0,0,0,0};
  #pragma unroll
  for (int m2 = 0; m2 < 8; ++m2){
    #pragma unroll
    for (int n2 = 0; n2 < 4; ++n2){
      const int gc  = colg0 + n2*16 + (lane & 15);
      const float bvv = bias[gc];
      #pragma unroll
      for (int j = 0; j < 4; ++j){
        float yv = acc[m2][n2][j] + bvv;
        size_t gr = mbase + m2*16 + (lane>>4)*4 + j;
        Y[gr*256 + gc] = f2bf(yv);
        spart[n2] += yv;
        qpart[n2] = __fmaf_rn(yv, yv, qpart[n2]);
      }
    }
  }
  #pragma unroll
  for (int n2 = 0; n2 < 4; ++n2){
    float s = spart[n2], q = qpart[n2];
    s += __shfl_xor(s, 16); q += __shfl_xor(q, 16);
    s += __shfl_xor(s, 32); q += __shfl_xor(q, 32);
    if (lane < 16){
      int gc = colg0 + n2*16 + lane;
      atomicAdd(&osum[gc], s);
      atomicAdd(&osq[gc], q);
    }
  }
}

// ------------- final BN1 + ReLU -> fp32 out (BN finalize folded in) -------------
__global__ __launch_bounds__(256) void apply_kernel(
    const unsigned short* __restrict__ y,
    const float* __restrict__ s1sum, const float* __restrict__ s1sq,
    const float* __restrict__ g, const float* __restrict__ bt,
    float* __restrict__ out)
{
  __shared__ float ssc[256], ssh[256];
  {
    int c = threadIdx.x;
    float mean = s1sum[c] * (1.0f/65536.0f);
    float var  = s1sq[c] * (1.0f/65536.0f) - mean*mean;
    float s = g[c] / sqrtf(var + 1e-5f);
    ssc[c] = s;
    ssh[c] = __fmaf_rn(-mean, s, bt[c]);
  }
  __syncthreads();
  const int t = blockIdx.x*256 + threadIdx.x;
  const size_t base = (size_t)t * 8;
  const int c0 = (int)(base & 255);
  short8 v = *reinterpret_cast<const short8*>(y + base);
  float r[8];
  #pragma unroll
  for (int j = 0; j < 8; ++j){
    float f = bf2f((unsigned short)v[j]);
    f = __fmaf_rn(f, ssc[c0+j], ssh[c0+j]);
    r[j] = fmaxf(f, 0.0f);
  }
  float4 o0, o1;
  o0.x=r[0]; o0.y=r[1]; o0.z=r[2]; o0.w=r[3];
  o1.x=r[4]; o1.y=r[5]; o1.z=r[6]; o1.w=r[7];
  *reinterpret_cast<float4*>(out + base)     = o0;
  *reinterpret_cast<float4*>(out + base + 4) = o1;
}

// ---------------- workspace layout ----------------
constexpr size_t WS_STATS = 0;                                  // 4*256 f32
constexpr size_t WS_W0B   = 8192;                               // 98304 bf16
constexpr size_t WS_W1B   = WS_W0B + 196608;                    // 65536 bf16
constexpr size_t WS_KW    = WS_W1B + 131072;                    // M*3 f32
constexpr size_t WS_KI    = WS_KW + 786432;                     // M*3 i32
constexpr size_t WS_X     = 4194304;                            // M*384 bf16 (50.3 MB)
constexpr size_t WS_Y0    = WS_X + (size_t)MTOT*CINn*2;         // M*256 bf16 (33.5 MB)
// Y1 reuses the X region (X dead after GEMM0). Peak ws ~ 88 MB.

extern "C" void kernel_launch(void* const* d_in, const int* in_sizes, int n_in,
                              void* d_out, int out_size, void* d_ws, size_t ws_size,
                              hipStream_t stream)
{
  const float* sxyz  = (const float*)d_in[0];
  const float* sfeat = (const float*)d_in[1];
  const float* oxyz  = (const float*)d_in[2];
  const float* ofeat = (const float*)d_in[3];
  const float* w0    = (const float*)d_in[4];
  const float* b0    = (const float*)d_in[5];
  const float* g0    = (const float*)d_in[6];
  const float* bt0   = (const float*)d_in[7];
  const float* w1    = (const float*)d_in[8];
  const float* b1    = (const float*)d_in[9];
  const float* g1    = (const float*)d_in[10];
  const float* bt1   = (const float*)d_in[11];
  // d_in[12] = k (always 3, hard-coded)

  char* ws = (char*)d_ws;
  float* stats  = (float*)(ws + WS_STATS);   // sum0,ssq0,sum1,ssq1
  unsigned short* w0b = (unsigned short*)(ws + WS_W0B);
  unsigned short* w1b = (unsigned short*)(ws + WS_W1B);
  float* kw = (float*)(ws + WS_KW);
  int*   ki = (int*)(ws + WS_KI);
  unsigned short* X  = (unsigned short*)(ws + WS_X);
  unsigned short* Y0 = (unsigned short*)(ws + WS_Y0);
  unsigned short* Y1 = (unsigned short*)(ws + WS_X);   // reuse

  hipMemsetAsync(stats, 0, 4*256*sizeof(float), stream);
  cvtw_kernel<<<640, 256, 0, stream>>>(w0, w1, w0b, w1b);
  knn_kernel<<<1024, 128, 0, stream>>>(sxyz, oxyz, kw, ki);
  interp_kernel<<<MTOT/16, 256, 0, stream>>>(sfeat, ofeat, kw, ki, X);
  gemm_kernel<CINn, false><<<MTOT/128, 256, 0, stream>>>(
      X, w0b, b0, nullptr, nullptr, nullptr, nullptr, Y0, stats, stats + 256);
  gemm_kernel<256, true><<<MTOT/128, 256, 0, stream>>>(
      Y0, w1b, b1, stats, stats + 256, g0, bt0, Y1, stats + 512, stats + 768);
  apply_kernel<<<(MTOT*256)/(256*8), 256, 0, stream>>>(
      Y1, stats + 512, stats + 768, g1, bt1, (float*)d_out);
}

// Round 8
// 275.191 us; speedup vs baseline: 1.1516x; 1.1516x over previous
//
#include <hip/hip_runtime.h>
#include <hip/hip_bf16.h>
#include <cstdint>
#include <cstddef>

// Problem constants (fixed shapes)
#define Bn   4
#define Sn   4096
#define Nn   16384
#define CSn  256
#define COn  128
#define CINn 384
#define MTOT 65536   // B*N

using short8 = short __attribute__((ext_vector_type(8)));
using f32x4  = float __attribute__((ext_vector_type(4)));
using f32x2  = float __attribute__((ext_vector_type(2)));

static __device__ __forceinline__ float bf2f(unsigned short u){
  unsigned int x = ((unsigned int)u) << 16;
  return __builtin_bit_cast(float, x);
}
static __device__ __forceinline__ unsigned short f2bf(float f){
  unsigned int x = __builtin_bit_cast(unsigned int, f);
  x += 0x7fffu + ((x >> 16) & 1u);   // RNE
  return (unsigned short)(x >> 16);
}

// ---------------- KNN ----------------
// branchy insert used only in the tiny merges
static __device__ __forceinline__ void top3_insert(float d, int s,
    float& d0, float& d1, float& d2, int& i0, int& i1, int& i2){
  if (d < d2){
    if (d < d1){
      d2 = d1; i2 = i1;
      if (d < d0){ d1 = d0; i1 = i0; d0 = d; i0 = s; }
      else       { d1 = d;  i1 = s; }
    } else { d2 = d; i2 = s; }
  }
}

// branch-free top3 maintenance (R6-verified): strict '<', ascending scan order
static __device__ __forceinline__ void top3_bf(float dd, int sidx,
    float& d0, float& d1, float& d2, int& i0, int& i1, int& i2){
  const bool c0 = dd < d0, c1 = dd < d1, c2 = dd < d2;
  const float od0 = d0, od1 = d1;
  d0 = fminf(dd, od0);
  d1 = __builtin_amdgcn_fmed3f(dd, od0, od1);
  d2 = __builtin_amdgcn_fmed3f(dd, od1, d2);
  i2 = c2 ? (c1 ? i1 : sidx) : i2;    // old i1
  i1 = c1 ? (c0 ? i0 : sidx) : i1;    // old i0
  i0 = c0 ? sidx : i0;
}

// 1024 blocks x 256 threads (4 waves). Block = 64 queries (lane = query);
// wave w scans S-quarter [w*1024,(w+1)*1024), split into chain A = first 512
// and chain B = second 512 (all A indices < all B indices -> strict-'<'
// A-then-B merge preserves top_k tie-break). Keys staged per-wave into
// double-buffered LDS chunks of 128 pairs, TWO CONTIGUOUS PLANES:
//   plane0[i] = {xA, xB, yA, yB}   plane1[i] = {zA, zB, ssA, ssB}
// Staging writes are lane-contiguous 16B (plane[l], plane[l+64]) -> conflict-
// free (R7's 32B-stride writes were a 4-way conflict, 524K counted). Scan
// reads are wave-uniform ds_read_b128 -> pure broadcast. Distance math runs
// PACKED (f32x2, 2 keys/op); per-component rounding identical to scalar:
// fma(-2, dot, add(qq,ss)), dot = fma(z, fma(y, mul(x))) -> bit-exact vs
// rounds 1-7 (no tie flips). No barriers in the main loop (wave-private
// buffers); async-split staging: next chunk's global loads issue before the
// scan, ds_writes after.
__global__ __launch_bounds__(256) void knn_kernel(
    const float* __restrict__ sxyz, const float* __restrict__ oxyz,
    float* __restrict__ kw, int* __restrict__ ki)
{
  __shared__ float4 cb[4][2][2][128];   // 32 KB: [wave][dbuf][plane][pair]
  __shared__ float  md[4][64][3];
  __shared__ int    mi[4][64][3];

  const int b    = blockIdx.x >> 8;      // 256 blocks per batch
  const int qblk = blockIdx.x & 255;
  const int lane = threadIdx.x & 63;
  const int wave = threadIdx.x >> 6;     // 0..3 = S-quarter
  const int n    = qblk*64 + lane;
  const float* op = oxyz + ((size_t)b*Nn + n)*3;
  const float px = op[0], py = op[1], pz = op[2];
  const float qq = __fadd_rn(__fadd_rn(__fmul_rn(px,px), __fmul_rn(py,py)), __fmul_rn(pz,pz));
  const f32x2 px2 = {px,px}, py2 = {py,py}, pz2 = {pz,pz}, qq2 = {qq,qq};
  const f32x2 m2  = {-2.0f,-2.0f};

  const float* sx = sxyz + (size_t)b*Sn*3;
  const int qb = wave*1024;              // quarter base; A:[qb,qb+512) B:+512

  float ax[2], ay[2], az[2], bx[2], by[2], bz[2];

  // load chunk-0 keys (2 A + 2 B per lane)
  #pragma unroll
  for (int it = 0; it < 2; ++it){
    int j  = it*64 + lane;
    int ja = qb + j, jb = ja + 512;
    ax[it]=sx[ja*3+0]; ay[it]=sx[ja*3+1]; az[it]=sx[ja*3+2];
    bx[it]=sx[jb*3+0]; by[it]=sx[jb*3+1]; bz[it]=sx[jb*3+2];
  }
  // write chunk 0 (contiguous 16B per lane per plane)
  #pragma unroll
  for (int it = 0; it < 2; ++it){
    int j = it*64 + lane;
    float assv = __fadd_rn(__fadd_rn(__fmul_rn(ax[it],ax[it]), __fmul_rn(ay[it],ay[it])), __fmul_rn(az[it],az[it]));
    float bssv = __fadd_rn(__fadd_rn(__fmul_rn(bx[it],bx[it]), __fmul_rn(by[it],by[it])), __fmul_rn(bz[it],bz[it]));
    cb[wave][0][0][j] = make_float4(ax[it], bx[it], ay[it], by[it]);
    cb[wave][0][1][j] = make_float4(az[it], bz[it], assv, bssv);
  }

  float dA0=3.4e38f,dA1=3.4e38f,dA2=3.4e38f; int iA0=0,iA1=0,iA2=0;
  float dB0=3.4e38f,dB1=3.4e38f,dB2=3.4e38f; int iB0=0,iB1=0,iB2=0;

  int cur = 0;
  for (int c = 0; c < 4; ++c){
    if (c < 3){                          // issue next chunk's loads EARLY
      #pragma unroll
      for (int it = 0; it < 2; ++it){
        int j  = (c+1)*128 + it*64 + lane;
        int ja = qb + j, jb = ja + 512;
        ax[it]=sx[ja*3+0]; ay[it]=sx[ja*3+1]; az[it]=sx[ja*3+2];
        bx[it]=sx[jb*3+0]; by[it]=sx[jb*3+1]; bz[it]=sx[jb*3+2];
      }
    }
    const int base = qb + c*128;         // chain-A index base this chunk
    #pragma unroll 8
    for (int i = 0; i < 128; ++i){
      float4 lo = cb[wave][cur][0][i];   // broadcast b128
      float4 hi = cb[wave][cur][1][i];
      f32x2 kx2  = {lo.x, lo.y};
      f32x2 ky2  = {lo.z, lo.w};
      f32x2 kz2  = {hi.x, hi.y};
      f32x2 kss2 = {hi.z, hi.w};
      f32x2 dot = kx2 * px2;
      dot = __builtin_elementwise_fma(ky2, py2, dot);
      dot = __builtin_elementwise_fma(kz2, pz2, dot);
      f32x2 sm = qq2 + kss2;
      f32x2 dd = __builtin_elementwise_fma(m2, dot, sm);
      top3_bf(dd.x, base + i,       dA0,dA1,dA2, iA0,iA1,iA2);
      top3_bf(dd.y, base + i + 512, dB0,dB1,dB2, iB0,iB1,iB2);
    }
    if (c < 3){                          // write next chunk AFTER the scan
      int nxt = cur ^ 1;
      #pragma unroll
      for (int it = 0; it < 2; ++it){
        int j = it*64 + lane;
        float assv = __fadd_rn(__fadd_rn(__fmul_rn(ax[it],ax[it]), __fmul_rn(ay[it],ay[it])), __fmul_rn(az[it],az[it]));
        float bssv = __fadd_rn(__fadd_rn(__fmul_rn(bx[it],bx[it]), __fmul_rn(by[it],by[it])), __fmul_rn(bz[it],bz[it]));
        cb[wave][nxt][0][j] = make_float4(ax[it], bx[it], ay[it], by[it]);
        cb[wave][nxt][1][j] = make_float4(az[it], bz[it], assv, bssv);
      }
      cur = nxt;
    }
  }

  // per-wave A/B merge: all A indices < all B indices -> strict '<' correct
  {
    float e0=dA0, e1=dA1, e2=dA2; int j0=iA0, j1=iA1, j2=iA2;
    top3_insert(dB0, iB0, e0,e1,e2, j0,j1,j2);
    top3_insert(dB1, iB1, e0,e1,e2, j0,j1,j2);
    top3_insert(dB2, iB2, e0,e1,e2, j0,j1,j2);
    md[wave][lane][0]=e0; md[wave][lane][1]=e1; md[wave][lane][2]=e2;
    mi[wave][lane][0]=j0; mi[wave][lane][1]=j1; mi[wave][lane][2]=j2;
  }
  __syncthreads();
  if (threadIdx.x < 64){
    float e0=md[0][lane][0], e1=md[0][lane][1], e2=md[0][lane][2];
    int   j0=mi[0][lane][0], j1=mi[0][lane][1], j2=mi[0][lane][2];
    #pragma unroll
    for (int w = 1; w < 4; ++w){         // ascending quarters: tie-break safe
      top3_insert(md[w][lane][0], mi[w][lane][0], e0,e1,e2, j0,j1,j2);
      top3_insert(md[w][lane][1], mi[w][lane][1], e0,e1,e2, j0,j1,j2);
      top3_insert(md[w][lane][2], mi[w][lane][2], e0,e1,e2, j0,j1,j2);
    }
    float wa = 1.0f/(e0+1e-8f), wb = 1.0f/(e1+1e-8f), wc = 1.0f/(e2+1e-8f);
    float sm = __fadd_rn(__fadd_rn(wa, wb), wc);
    size_t base = ((size_t)b*Nn + n)*3;
    kw[base+0] = wa/sm; kw[base+1] = wb/sm; kw[base+2] = wc/sm;
    ki[base+0] = j0;    ki[base+1] = j1;    ki[base+2] = j2;
  }
}

// ------------- interpolate + concat -> x [M][384] bf16 -------------
__global__ __launch_bounds__(256) void interp_kernel(
    const float* __restrict__ sfeat, const float* __restrict__ ofeat,
    const float* __restrict__ kw, const int* __restrict__ ki,
    unsigned short* __restrict__ X)
{
  const int c  = threadIdx.x;          // channel 0..255
  const int m0 = blockIdx.x * 16;      // 16 points per block
  for (int p = 0; p < 16; ++p){
    const int m = m0 + p;
    const int b = m >> 14;             // N = 16384
    const float w0v = kw[(size_t)m*3+0], w1v = kw[(size_t)m*3+1], w2v = kw[(size_t)m*3+2];
    const int   i0  = ki[(size_t)m*3+0], i1  = ki[(size_t)m*3+1], i2  = ki[(size_t)m*3+2];
    const float* sb = sfeat + (size_t)b * Sn * CSn;
    float v = __fmaf_rn(w2v, sb[(size_t)i2*CSn + c],
              __fmaf_rn(w1v, sb[(size_t)i1*CSn + c],
              __fmul_rn(w0v, sb[(size_t)i0*CSn + c])));
    X[(size_t)m*CINn + COn + c] = f2bf(v);
    if (c < COn) X[(size_t)m*CINn + c] = f2bf(ofeat[(size_t)m*COn + c]);
  }
}

// ------------- fp32 -> bf16 weight conversion -------------
__global__ __launch_bounds__(256) void cvtw_kernel(
    const float* __restrict__ w0, const float* __restrict__ w1,
    unsigned short* __restrict__ w0b, unsigned short* __restrict__ w1b)
{
  int i = blockIdx.x*256 + threadIdx.x;
  if (i < 256*384) w0b[i] = f2bf(w0[i]);
  int j = i - 256*384;
  if (j >= 0 && j < 256*256) w1b[j] = f2bf(w1[j]);
}

// ------------- GEMM: Y[M][256] = A[M][KDIM] @ W[256][KDIM]^T + bias ----------
// BM=128, BN=256 (full), BK=64. 4 waves, wave w owns cols [w*64, w*64+64).
// BNRELU prologue computes BN0 scale/shift IN-KERNEL from gemm0's stats
// (bnfin kernel folded away), then A' = relu(A*scale + shift) during staging.
// Epilogue: bf16 store + per-channel sum/sumsq atomics for BN stats.
template<int KDIM, bool BNRELU>
__global__ __launch_bounds__(256) void gemm_kernel(
    const unsigned short* __restrict__ A,
    const unsigned short* __restrict__ W,
    const float* __restrict__ bias,
    const float* __restrict__ s0sum,
    const float* __restrict__ s0sq,
    const float* __restrict__ bng,
    const float* __restrict__ bnbt,
    unsigned short* __restrict__ Y,
    float* __restrict__ osum,
    float* __restrict__ osq)
{
  __shared__ unsigned short As[128*64];   // 16 KB, XOR-swizzled 16B chunks
  __shared__ unsigned short Bs[256*64];   // 32 KB
  __shared__ float lsc[256], lsh[256];
  const int tid  = threadIdx.x;
  const int lane = tid & 63;
  const int wave = tid >> 6;
  const size_t mbase = (size_t)blockIdx.x * 128;
  if constexpr (BNRELU){
    float mean = s0sum[tid] * (1.0f/65536.0f);
    float var  = s0sq[tid] * (1.0f/65536.0f) - mean*mean;
    float s = bng[tid] / sqrtf(var + 1e-5f);
    lsc[tid] = s;
    lsh[tid] = __fmaf_rn(-mean, s, bnbt[tid]);
  }
  f32x4 acc[8][4];
  #pragma unroll
  for (int m2 = 0; m2 < 8; ++m2)
    #pragma unroll
    for (int n2 = 0; n2 < 4; ++n2) acc[m2][n2] = f32x4{0.f,0.f,0.f,0.f};
  __syncthreads();

  for (int k0 = 0; k0 < KDIM; k0 += 64){
    if (k0) __syncthreads();
    // stage A: 128 rows x 8 chunks(16B) = 1024 chunks, 4/thread
    #pragma unroll
    for (int i = 0; i < 4; ++i){
      int cid = tid + 256*i;
      int row = cid >> 3, c8 = cid & 7;
      short8 v = *reinterpret_cast<const short8*>(A + (mbase+row)*KDIM + k0 + c8*8);
      if constexpr (BNRELU){
        #pragma unroll
        for (int j = 0; j < 8; ++j){
          int kc = k0 + c8*8 + j;
          float f = bf2f((unsigned short)v[j]);
          f = fmaxf(__fmaf_rn(f, lsc[kc], lsh[kc]), 0.0f);
          v[j] = (short)f2bf(f);
        }
      }
      *reinterpret_cast<short8*>(reinterpret_cast<char*>(As) + row*128 + ((c8 ^ (row&7)) << 4)) = v;
    }
    // stage B (weights): 256 rows x 8 chunks = 2048 chunks, 8/thread
    #pragma unroll
    for (int i = 0; i < 8; ++i){
      int cid = tid + 256*i;
      int row = cid >> 3, c8 = cid & 7;
      short8 v = *reinterpret_cast<const short8*>(W + (size_t)row*KDIM + k0 + c8*8);
      *reinterpret_cast<short8*>(reinterpret_cast<char*>(Bs) + row*128 + ((c8 ^ (row&7)) << 4)) = v;
    }
    __syncthreads();
    #pragma unroll
    for (int kk = 0; kk < 2; ++kk){
      short8 af[8], bv[4];
      #pragma unroll
      for (int m2 = 0; m2 < 8; ++m2){
        int row = m2*16 + (lane & 15);
        int c8  = kk*4 + (lane >> 4);
        af[m2] = *reinterpret_cast<const short8*>(reinterpret_cast<char*>(As) + row*128 + ((c8 ^ (row&7)) << 4));
      }
      #pragma unroll
      for (int n2 = 0; n2 < 4; ++n2){
        int row = wave*64 + n2*16 + (lane & 15);
        int c8  = kk*4 + (lane >> 4);
        bv[n2] = *reinterpret_cast<const short8*>(reinterpret_cast<char*>(Bs) + row*128 + ((c8 ^ (row&7)) << 4));
      }
      #pragma unroll
      for (int m2 = 0; m2 < 8; ++m2)
        #pragma unroll
        for (int n2 = 0; n2 < 4; ++n2)
          acc[m2][n2] = __builtin_amdgcn_mfma_f32_16x16x32_bf16(af[m2], bv[n2], acc[m2][n2], 0, 0, 0);
    }
  }

  // epilogue: C/D layout col = lane&15, row = (lane>>4)*4 + j  [m89-verified]
  const int colg0 = wave*64;
  float spart[4] = {0,0,0,0}, qpart[4] = {0,0,0,0};
  #pragma unroll
  for (int m2 = 0; m2 < 8; ++m2){
    #pragma unroll
    for (int n2 = 0; n2 < 4; ++n2){
      const int gc  = colg0 + n2*16 + (lane & 15);
      const float bvv = bias[gc];
      #pragma unroll
      for (int j = 0; j < 4; ++j){
        float yv = acc[m2][n2][j] + bvv;
        size_t gr = mbase + m2*16 + (lane>>4)*4 + j;
        Y[gr*256 + gc] = f2bf(yv);
        spart[n2] += yv;
        qpart[n2] = __fmaf_rn(yv, yv, qpart[n2]);
      }
    }
  }
  #pragma unroll
  for (int n2 = 0; n2 < 4; ++n2){
    float s = spart[n2], q = qpart[n2];
    s += __shfl_xor(s, 16); q += __shfl_xor(q, 16);
    s += __shfl_xor(s, 32); q += __shfl_xor(q, 32);
    if (lane < 16){
      int gc = colg0 + n2*16 + lane;
      atomicAdd(&osum[gc], s);
      atomicAdd(&osq[gc], q);
    }
  }
}

// ------------- final BN1 + ReLU -> fp32 out (BN finalize folded in) -------------
__global__ __launch_bounds__(256) void apply_kernel(
    const unsigned short* __restrict__ y,
    const float* __restrict__ s1sum, const float* __restrict__ s1sq,
    const float* __restrict__ g, const float* __restrict__ bt,
    float* __restrict__ out)
{
  __shared__ float ssc[256], ssh[256];
  {
    int c = threadIdx.x;
    float mean = s1sum[c] * (1.0f/65536.0f);
    float var  = s1sq[c] * (1.0f/65536.0f) - mean*mean;
    float s = g[c] / sqrtf(var + 1e-5f);
    ssc[c] = s;
    ssh[c] = __fmaf_rn(-mean, s, bt[c]);
  }
  __syncthreads();
  const int t = blockIdx.x*256 + threadIdx.x;
  const size_t base = (size_t)t * 8;
  const int c0 = (int)(base & 255);
  short8 v = *reinterpret_cast<const short8*>(y + base);
  float r[8];
  #pragma unroll
  for (int j = 0; j < 8; ++j){
    float f = bf2f((unsigned short)v[j]);
    f = __fmaf_rn(f, ssc[c0+j], ssh[c0+j]);
    r[j] = fmaxf(f, 0.0f);
  }
  float4 o0, o1;
  o0.x=r[0]; o0.y=r[1]; o0.z=r[2]; o0.w=r[3];
  o1.x=r[4]; o1.y=r[5]; o1.z=r[6]; o1.w=r[7];
  *reinterpret_cast<float4*>(out + base)     = o0;
  *reinterpret_cast<float4*>(out + base + 4) = o1;
}

// ---------------- workspace layout ----------------
constexpr size_t WS_STATS = 0;                                  // 4*256 f32
constexpr size_t WS_W0B   = 8192;                               // 98304 bf16
constexpr size_t WS_W1B   = WS_W0B + 196608;                    // 65536 bf16
constexpr size_t WS_KW    = WS_W1B + 131072;                    // M*3 f32
constexpr size_t WS_KI    = WS_KW + 786432;                     // M*3 i32
constexpr size_t WS_X     = 4194304;                            // M*384 bf16 (50.3 MB)
constexpr size_t WS_Y0    = WS_X + (size_t)MTOT*CINn*2;         // M*256 bf16 (33.5 MB)
// Y1 reuses the X region (X dead after GEMM0). Peak ws ~ 88 MB.

extern "C" void kernel_launch(void* const* d_in, const int* in_sizes, int n_in,
                              void* d_out, int out_size, void* d_ws, size_t ws_size,
                              hipStream_t stream)
{
  const float* sxyz  = (const float*)d_in[0];
  const float* sfeat = (const float*)d_in[1];
  const float* oxyz  = (const float*)d_in[2];
  const float* ofeat = (const float*)d_in[3];
  const float* w0    = (const float*)d_in[4];
  const float* b0    = (const float*)d_in[5];
  const float* g0    = (const float*)d_in[6];
  const float* bt0   = (const float*)d_in[7];
  const float* w1    = (const float*)d_in[8];
  const float* b1    = (const float*)d_in[9];
  const float* g1    = (const float*)d_in[10];
  const float* bt1   = (const float*)d_in[11];
  // d_in[12] = k (always 3, hard-coded)

  char* ws = (char*)d_ws;
  float* stats  = (float*)(ws + WS_STATS);   // sum0,ssq0,sum1,ssq1
  unsigned short* w0b = (unsigned short*)(ws + WS_W0B);
  unsigned short* w1b = (unsigned short*)(ws + WS_W1B);
  float* kw = (float*)(ws + WS_KW);
  int*   ki = (int*)(ws + WS_KI);
  unsigned short* X  = (unsigned short*)(ws + WS_X);
  unsigned short* Y0 = (unsigned short*)(ws + WS_Y0);
  unsigned short* Y1 = (unsigned short*)(ws + WS_X);   // reuse

  hipMemsetAsync(stats, 0, 4*256*sizeof(float), stream);
  cvtw_kernel<<<640, 256, 0, stream>>>(w0, w1, w0b, w1b);
  knn_kernel<<<1024, 256, 0, stream>>>(sxyz, oxyz, kw, ki);
  interp_kernel<<<MTOT/16, 256, 0, stream>>>(sfeat, ofeat, kw, ki, X);
  gemm_kernel<CINn, false><<<MTOT/128, 256, 0, stream>>>(
      X, w0b, b0, nullptr, nullptr, nullptr, nullptr, Y0, stats, stats + 256);
  gemm_kernel<256, true><<<MTOT/128, 256, 0, stream>>>(
      Y0, w1b, b1, stats, stats + 256, g0, bt0, Y1, stats + 512, stats + 768);
  apply_kernel<<<(MTOT*256)/(256*8), 256, 0, stream>>>(
      Y1, stats + 512, stats + 768, g1, bt1, (float*)d_out);
}